// Round 6
// baseline (434.464 us; speedup 1.0000x reference)
//
#include <hip/hip_runtime.h>
#include <cstdint>

#define NROW 6144
#define KDIM 128
#define NLAB 200
#define C_COEF (-0.28719499063341177f)   /* -ln(99)/16 ; A_COEF = 2 exactly */
#define UBV 64.0f

typedef _Float16 f16x8 __attribute__((ext_vector_type(8)));
typedef float f32x4 __attribute__((ext_vector_type(4)));
typedef __attribute__((address_space(1))) const void as1c_void;
typedef __attribute__((address_space(3))) void as3_void;

__device__ __forceinline__ float softplus_f(float x){
  return fmaxf(x, 0.f) + __logf(1.f + __expf(-fabsf(x)));
}
__device__ __forceinline__ float waveRedF(float v){
#pragma unroll
  for (int o = 32; o; o >>= 1) v += __shfl_down(v, o, 64);
  return v;
}
__device__ __forceinline__ int waveRedI(int v){
#pragma unroll
  for (int o = 32; o; o >>= 1) v += __shfl_down(v, o, 64);
  return v;
}
__device__ __forceinline__ int bucket_of(float v){
  int b = (int)fmaf(v, 2.f, 128.f);        // trunc==floor for the unclamped range
  return b < 0 ? 0 : (b > 255 ? 255 : b);
}
__device__ __forceinline__ unsigned key16_of(_Float16 h){
  unsigned short b = __builtin_bit_cast(unsigned short, h);
  return (b & 0x8000u) ? (unsigned)((unsigned short)~b) : (unsigned)(b | 0x8000u);
}
__device__ __forceinline__ float key16_dec(unsigned k){
  unsigned short b = (k & 0x8000u) ? (unsigned short)(k & 0x7FFFu)
                                   : (unsigned short)(~k & 0xFFFFu);
  return (float)__builtin_bit_cast(_Float16, b);
}

// ---------------- labels + per-label histogram + member lists ----------------
__global__ void k_label(const int* __restrict__ y, unsigned char* __restrict__ lab,
                        int* __restrict__ cnt, int* __restrict__ simIdx){
  const int row = blockIdx.x;
  const int t = threadIdx.x;
  if (t < NLAB){
    if (y[(size_t)row * NLAB + t] != 0){
      lab[row] = (unsigned char)t;
      int p = atomicAdd(&cnt[t], 1);
      if (p < 512) simIdx[t * 512 + p] = row;
    }
  }
}

// ---------------- per-class 6144-bit similarity masks ----------------
__global__ __launch_bounds__(192) void k_clsmask(const unsigned char* __restrict__ lab,
                                                 unsigned* __restrict__ cm){
  const int c = blockIdx.x;       // class
  const int w = threadIdx.x;      // word: rows [w*32, w*32+32)
  const uint4* p = (const uint4*)(lab + w * 32);
  uint4 a = p[0], b = p[1];
  unsigned words[8] = {a.x, a.y, a.z, a.w, b.x, b.y, b.z, b.w};
  unsigned bits = 0;
#pragma unroll
  for (int j = 0; j < 8; j++)
#pragma unroll
    for (int i = 0; i < 4; i++)
      if (((words[j] >> (8 * i)) & 255u) == (unsigned)c) bits |= 1u << (4 * j + i);
  cm[c * 192 + w] = bits;
}

// ---------------- tanh -> swizzled f16, + quantization-loss partial ----------------
__global__ __launch_bounds__(256) void k_tanh(const float* __restrict__ u,
    _Float16* __restrict__ uhswz, float* __restrict__ accf){
  const int tid = threadIdx.x;
  const int gid = blockIdx.x * 256 + tid;
  const int row = gid >> 4;
  const int h = gid & 15;
  const int g = h ^ (row & 7);
  const float* sp = u + (size_t)row * KDIM + g * 8;
  float q = 0.f;
  f16x8 o;
#pragma unroll
  for (int t = 0; t < 8; t++){
    float x = sp[t];
    float e2 = __expf(2.f * x);
    float th = 1.f - 2.f * __builtin_amdgcn_rcpf(e2 + 1.f);  // tanh, ~1e-6 err
    float sg = (th > 0.f) ? 1.f : ((th < 0.f) ? -1.f : 0.f);
    float d = th - sg;
    q += d * d;
    o[t] = (_Float16)th;
  }
  *(f16x8*)(uhswz + (size_t)row * KDIM + h * 8) = o;
  q = waveRedF(q);
  __shared__ float qb[4];
  if ((tid & 63) == 0) qb[tid >> 6] = q;
  __syncthreads();
  if (tid == 0) atomicAdd(&accf[0], qb[0] + qb[1] + qb[2] + qb[3]);
}

// ---------------- inner = uh @ uh^T -> f16 out via LDS-transpose epilogue ----------------
__global__ __launch_bounds__(256) void k_mm(const _Float16* __restrict__ A,
    _Float16* __restrict__ out, int row0){
  __shared__ __align__(16) _Float16 SH[2 * 128 * KDIM];   // 64 KB: As|Bs, reused as Cs
  _Float16* As = SH;
  _Float16* Bs = SH + 128 * KDIM;
  const int tid = threadIdx.x;
  const int wav = tid >> 6, lane = tid & 63;
  const int bj = blockIdx.x, bi = blockIdx.y;

  const char* Ag = (const char*)(A + (size_t)(row0 + bi * 128) * KDIM);
  const char* Bg = (const char*)(A + (size_t)(bj * 128) * KDIM);
  char* Asb = (char*)As;
  char* Bsb = (char*)Bs;
#pragma unroll
  for (int t = 0; t < 8; t++){
    const int ub = wav * 8192 + t * 1024;
    __builtin_amdgcn_global_load_lds((as1c_void*)(Ag + ub + lane * 16),
                                     (as3_void*)(Asb + ub), 16, 0, 0);
    __builtin_amdgcn_global_load_lds((as1c_void*)(Bg + ub + lane * 16),
                                     (as3_void*)(Bsb + ub), 16, 0, 0);
  }
  __syncthreads();

  const int quad = lane >> 4, l16 = lane & 15;
  const int wm = (wav >> 1) * 64, wn = (wav & 1) * 64;
  f32x4 acc[4][4];
#pragma unroll
  for (int im = 0; im < 4; im++)
#pragma unroll
    for (int in = 0; in < 4; in++)
      acc[im][in] = (f32x4){0.f, 0.f, 0.f, 0.f};

#pragma unroll
  for (int kb = 0; kb < 4; kb++){
    f16x8 af[4], bf[4];
#pragma unroll
    for (int i = 0; i < 4; i++){
      const int m = wm + i * 16 + l16;
      const int gidx = kb * 4 + quad;
      af[i] = *(const f16x8*)(Asb + m * 256 + ((gidx ^ (m & 7)) << 4));
      const int n = wn + i * 16 + l16;
      bf[i] = *(const f16x8*)(Bsb + n * 256 + ((gidx ^ (n & 7)) << 4));
    }
#pragma unroll
    for (int im = 0; im < 4; im++)
#pragma unroll
      for (int in = 0; in < 4; in++)
        acc[im][in] = __builtin_amdgcn_mfma_f32_16x16x32_f16(af[im], bf[in], acc[im][in], 0, 0, 0);
  }
  __syncthreads();                                 // done reading As/Bs

  _Float16* Cs = SH;                               // 128*132*2 = 33792 B
#pragma unroll
  for (int im = 0; im < 4; im++)
#pragma unroll
    for (int in = 0; in < 4; in++)
#pragma unroll
      for (int r = 0; r < 4; r++){
        const int rl = wm + im * 16 + quad * 4 + r;
        const int cl = wn + in * 16 + l16;
        Cs[rl * 132 + cl] = (_Float16)acc[im][in][r];
      }
  __syncthreads();

  _Float16* obase = out + (size_t)(bi * 128) * NROW + (size_t)bj * 128;
  const int s = tid & 15;
#pragma unroll
  for (int i = 0; i < 8; i++){
    const int r = (tid >> 4) + i * 16;
    f16x8 vv = *(const f16x8*)(Cs + r * 132 + s * 8);
    *(f16x8*)(obase + (size_t)r * NROW + s * 8) = vv;
  }
}

// ---------------- per-row stats + loss: ONE ROW PER WAVE, zero barriers ----------------
// Row in 48 VGPRs/lane (12 x f16x8, lane owns elems [(j*64+lane)*8, +8)).
// Per-wave LDS: hist(1KB) + cand(2KB) + simv(2KB) + ctl. Wave-synchronous
// LDS (threadfence_block = waitcnt, no barrier). Exact tie arithmetic.
__global__ __launch_bounds__(256) void k_stats(const _Float16* __restrict__ buf,
    const unsigned char* __restrict__ lab, const int* __restrict__ cnt,
    const int* __restrict__ simIdx, const unsigned* __restrict__ cm,
    float* __restrict__ accf, int* __restrict__ acci, int row0){
  __shared__ int histS[4 * 256];
  __shared__ float candS[4 * 512];
  __shared__ float simvS[4 * 512];
  __shared__ int ctlS[4 * 16];
  __shared__ float ctlFS[4 * 16];

  const int tid = threadIdx.x;
  const int lane = tid & 63;
  const int wav = tid >> 6;
  int* hist = histS + wav * 256;
  float* cand = candS + wav * 512;
  float* simv = simvS + wav * 512;
  int* ctl = ctlS + wav * 16;
  float* ctlF = ctlFS + wav * 16;

  const int lrow = blockIdx.x * 4 + wav;          // local row in chunk
  const int row = row0 + lrow;
  const int myl = lab[row];
  const int n_sim = cnt[myl];
  const int n_dis = NROW - n_sim;
  if (n_dis == 0 || n_sim == 0) return;           // per-wave exit (no barriers in kernel)
  const int k1 = n_dis - (n_dis * 9) / 10;        // tail count (top-10% dissimilar)
  const int k2 = n_sim - (n_sim * 9) / 10;        // head count (bottom-10% similar)
  const int ns = (n_sim < 512) ? n_sim : 512;

#pragma unroll
  for (int i = 0; i < 4; i++) hist[lane + 64 * i] = 0;
  if (lane < 16){ ctl[lane] = 0; ctlF[lane] = 0.f; }
  __threadfence_block();

  // ---- load row -> registers, mask bytes ----
  const f16x8* src = (const f16x8*)(buf + (size_t)lrow * NROW);
  const unsigned* cmr = cm + (size_t)myl * 192;
  f16x8 h[12];
  unsigned char gm[12];
#pragma unroll
  for (int j = 0; j < 12; j++){
    h[j] = src[j * 64 + lane];
    gm[j] = (unsigned char)((cmr[j * 16 + (lane >> 2)] >> (8 * (lane & 3))) & 255u);
  }

  // ---- P0: histogram + total sum (register sweep) ----
  float sumAll = 0.f;
#pragma unroll
  for (int j = 0; j < 12; j++)
#pragma unroll
    for (int e = 0; e < 8; e++){
      float v = (float)h[j][e];
      sumAll += v;
      atomicAdd(&hist[bucket_of(v)], 1);
    }

  // ---- sim gather (global, ~31 scattered 2B loads) + histogram correction ----
  const _Float16* rowp = buf + (size_t)lrow * NROW;
  float sumS = 0.f;
  for (int t = lane; t < ns; t += 64){
    int idx = simIdx[myl * 512 + t];
    float v = (float)rowp[idx];
    simv[t] = v;
    sumS += v;
    atomicAdd(&hist[bucket_of(v)], -1);
  }
  sumAll = __shfl(waveRedF(sumAll), 0, 64);
  sumS = __shfl(waveRedF(sumS), 0, 64);
  const float sumDS = sumAll - sumS;
  __threadfence_block();

  // ---- pivot bucket select (wave suffix-scan over 256 buckets) ----
  int c4[4]; int part = 0;
#pragma unroll
  for (int d = 0; d < 4; d++){ c4[d] = hist[4 * lane + d]; part += c4[d]; }
  int suf = part;
#pragma unroll
  for (int o = 1; o < 64; o <<= 1){ int x = __shfl_down(suf, o, 64); if (lane + o < 64) suf += x; }
  int cum = suf - part;                           // dissim count in buckets above group
#pragma unroll
  for (int d = 3; d >= 0; --d){
    if (k1 > cum && k1 <= cum + c4[d]){
      ctl[2] = k1 - cum;                          // rank within bucket (from top)
      ctl[3] = c4[d];                             // bucket population
      ctl[4] = 4 * lane + d;                      // pivot bucket
    }
    cum += c4[d];
  }
  __threadfence_block();
  const int kr0 = ctl[2], cntB = ctl[3], pb = ctl[4];
  const float thrLo = (pb == 0)   ? -1e30f : (float)(pb - 128) * 0.5f;
  const float thrHi = (pb == 255) ?  1e30f : (float)(pb - 127) * 0.5f;
  const bool smallB = (cntB <= 512);

  // ---- rescan: above-bucket sum + pivot-bucket compaction ----
  float sAb = 0.f;
#pragma unroll
  for (int j = 0; j < 12; j++){
    const unsigned mb = gm[j];
#pragma unroll
    for (int e = 0; e < 8; e++){
      if ((mb >> e) & 1) continue;
      float v = (float)h[j][e];
      if (v >= thrHi) sAb += v;
      else if (v >= thrLo && smallB){
        int p = atomicAdd(&ctl[1], 1);
        if (p < 512) cand[p] = v;
      }
    }
  }
  sAb = __shfl(waveRedF(sAb), 0, 64);
  __threadfence_block();

  float dSum;
  if (smallB){
    const int nc = ctl[1];                        // == cntB
    for (int t = lane; t < nc; t += 64){
      float vt = cand[t];
      int gt = 0, eq = 0;
      for (int j2 = 0; j2 < nc; j2++){
        float vj = cand[j2];
        gt += (vj > vt); eq += (vj == vt);
      }
      if (gt < kr0 && kr0 <= gt + eq){ ctlF[2] = vt; ctl[5] = gt; }
    }
    __threadfence_block();
    const float piv = ctlF[2];
    const int gtS = ctl[5];
    float sg = 0.f;
    for (int t = lane; t < nc; t += 64){
      float v = cand[t];
      if (v > piv) sg += v;
    }
    sg = __shfl(waveRedF(sg), 0, 64);
    dSum = sAb + sg + (float)(kr0 - gtS) * piv;
  } else {
    // guard (not expected): exact f16-key bisection within pivot bucket
    unsigned lo = 0u, hi = 65535u;
    while (lo < hi){
      unsigned mid = (lo + hi) >> 1;
      int c = 0;
#pragma unroll
      for (int j = 0; j < 12; j++){
        const unsigned mb = gm[j];
#pragma unroll
        for (int e = 0; e < 8; e++){
          if ((mb >> e) & 1) continue;
          float v = (float)h[j][e];
          if (v >= thrLo && v < thrHi && key16_of(h[j][e]) > mid) c++;
        }
      }
      c = __shfl(waveRedI(c), 0, 64);
      if (c >= kr0) lo = mid + 1; else hi = mid;
    }
    const float piv = key16_dec(lo);
    float sg = 0.f; int cg = 0;
#pragma unroll
    for (int j = 0; j < 12; j++){
      const unsigned mb = gm[j];
#pragma unroll
      for (int e = 0; e < 8; e++){
        if ((mb >> e) & 1) continue;
        float v = (float)h[j][e];
        if (v >= thrLo && v < thrHi && key16_of(h[j][e]) > lo){ sg += v; cg++; }
      }
    }
    sg = __shfl(waveRedF(sg), 0, 64);
    cg = __shfl(waveRedI(cg), 0, 64);
    dSum = sAb + sg + (float)(kr0 - cg) * piv;
  }

  // ---- sMin: k2-th smallest similar (exact rank-count on gathered list) ----
  for (int t = lane; t < ns; t += 64){
    float vt = simv[t];
    int lt = 0, eq = 0;
    for (int j2 = 0; j2 < ns; j2++){
      float vj = simv[j2];
      lt += (vj < vt); eq += (vj == vt);
    }
    if (lt < k2 && k2 <= lt + eq){ ctlF[5] = vt; ctl[6] = lt; }
  }
  __threadfence_block();
  const float piv2 = ctlF[5];
  const int ltS = ctl[6];
  float slt = 0.f;
  for (int t = lane; t < ns; t += 64){
    float v = simv[t];
    if (v < piv2) slt += v;
  }
  slt = __shfl(waveRedF(slt), 0, 64);
  const float sSum = slt + (float)(k2 - ltS) * piv2;

  // ---- BP/BPd (computed redundantly by all lanes) ----
  const float meanS = fminf(fmaxf(sumS / fmaxf((float)n_sim, 1.f), 0.f), UBV);
  const float meanDS = fminf(fmaxf(sumDS / fmaxf((float)n_dis, 1.f), 0.f), UBV);
  const float dMax = fminf(fmaxf(dSum / fmaxf((float)k1, 1.f), 0.f), UBV);
  const float sMin = fminf(fmaxf(sSum / fmaxf((float)k2, 1.f), 0.f), UBV);
  const float BP = meanS - (UBV - meanS) / UBV * fabsf(meanS - dMax);
  const float BPd = meanDS + meanDS / UBV * fabsf(meanDS - sMin);

  // ---- loss pass: register sweep (dissim) + sim side-loop ----
  float an = 0.f, cn = 0.f;
#pragma unroll
  for (int j = 0; j < 12; j++){
    const unsigned mb = gm[j];
#pragma unroll
    for (int e = 0; e < 8; e++){
      float v = (float)h[j][e];
      float dcd = v - BPd;
      float f = (v < BPd) ? C_COEF * dcd : (2.f * C_COEF) * dcd;
      float sp = softplus_f(-f);
      bool use = !((mb >> e) & 1) && (v != BPd);
      an += use ? sp : 0.f;
      cn += use ? 1.f : 0.f;
    }
  }
  float ap = 0.f, cp = 0.f;
  for (int t = lane; t < ns; t += 64){
    float v = simv[t];
    if (v != BP){
      float dc = v - BP;
      float f = (v > BP) ? C_COEF * dc : (2.f * C_COEF) * dc;
      ap += softplus_f(f); cp += 1.f;
    }
  }
  ap = waveRedF(ap); an = waveRedF(an); cp = waveRedF(cp); cn = waveRedF(cn);
  if (lane == 0){
    atomicAdd(&accf[1], ap / fmaxf(cp, 1.f));
    atomicAdd(&accf[2], an / fmaxf(cn, 1.f));
    atomicAdd(&acci[3], 1);
  }
}

__global__ void k_final(const float* __restrict__ accf, const int* __restrict__ acci,
                        float* __restrict__ out){
  if (threadIdx.x == 0 && blockIdx.x == 0){
    int c = acci[3];
    float posL = 0.f, navL = 0.f;
    if (c > 0){ posL = accf[1] / (float)c; navL = accf[2] / (float)c; }
    out[0] = posL + navL + 0.1f * (accf[0] / (float)(NROW * KDIM));
  }
}

extern "C" void kernel_launch(void* const* d_in, const int* in_sizes, int n_in,
                              void* d_out, int out_size, void* d_ws, size_t ws_size,
                              hipStream_t stream){
  const float* u = (const float*)d_in[0];
  const int* y = (const int*)d_in[1];
  char* ws = (char*)d_ws;
  float* accf = (float*)ws;                        // [0]=qSum [1]=posSum [2]=negSum
  int* acci = (int*)ws;                            // [3]=validCount
  int* cnt = (int*)(ws + 64);                      // 256 ints
  unsigned char* lab = (unsigned char*)(ws + 4096);        // 6144 B
  int* simIdx = (int*)(ws + 12288);                // 200*512 ints = 409600 B
  unsigned* cmask = (unsigned*)(ws + 425984);      // 200*192 u32 = 153600 B
  _Float16* uhswz = (_Float16*)(ws + 589824);      // 1572864 B
  const size_t ibufOff = 589824 + (size_t)NROW * KDIM * 2; // 2162688, 16B aligned
  _Float16* ibuf = (_Float16*)(ws + ibufOff);

  hipMemsetAsync(d_ws, 0, 4096, stream);           // accumulators + class counts
  k_label<<<NROW, 256, 0, stream>>>(y, lab, cnt, simIdx);
  k_clsmask<<<NLAB, 192, 0, stream>>>(lab, cmask);
  k_tanh<<<(NROW * 16) / 256, 256, 0, stream>>>(u, uhswz, accf);

  size_t avail = (ws_size > ibufOff) ? ws_size - ibufOff : 0;
  long maxRows = (long)(avail / ((size_t)NROW * 2));
  maxRows = (maxRows / 128) * 128;
  if (maxRows > NROW) maxRows = NROW;
  if (maxRows < 128) maxRows = 128;

  for (int r0 = 0; r0 < NROW; r0 += (int)maxRows){
    int rows = NROW - r0;
    if (rows > maxRows) rows = (int)maxRows;
    k_mm<<<dim3(48, rows / 128), 256, 0, stream>>>(uhswz, ibuf, r0);
    k_stats<<<rows / 4, 256, 0, stream>>>(ibuf, lab, cnt, simIdx, cmask, accf, acci, r0);
  }
  k_final<<<1, 64, 0, stream>>>(accf, acci, (float*)d_out);
}